// Round 7
// baseline (182.193 us; speedup 1.0000x reference)
//
#include <hip/hip_runtime.h>
#include <stdint.h>

// Problem constants (from setup_inputs: N=50000, T=401 -> 400 SDE steps, M=64)
#define N_PART  50000
#define HALF_N  25000
#define QUART_N 12500
#define STEPS   400
#define T_PTS   401
#define CHUNKS  20
#define SPC     (STEPS / CHUNKS)     // 20 steps per item
#define BITS_SPLIT 75000u            // threefry counter split: 150000 bits -> two halves
#define NSPLIT  8
#define BLK     256
#define SDE_ITEMS (CHUNKS * QUART_N) // 250000 threads, 2 pair-items each

// ---------------- Threefry-2x32 (exact JAX semantics, 20 rounds) ----------------
__device__ __forceinline__ void threefry2x32(uint32_t k0, uint32_t k1,
                                             uint32_t x0, uint32_t x1,
                                             uint32_t& o0, uint32_t& o1) {
  const uint32_t ks2 = k0 ^ k1 ^ 0x1BD11BDAu;
  x0 += k0; x1 += k1;
#define RND(r) { x0 += x1; x1 = (x1 << r) | (x1 >> (32 - r)); x1 ^= x0; }
  RND(13) RND(15) RND(26) RND(6)
  x0 += k1;  x1 += ks2 + 1u;
  RND(17) RND(29) RND(16) RND(24)
  x0 += ks2; x1 += k0 + 2u;
  RND(13) RND(15) RND(26) RND(6)
  x0 += k0;  x1 += k1 + 3u;
  RND(17) RND(29) RND(16) RND(24)
  x0 += k1;  x1 += ks2 + 4u;
  RND(13) RND(15) RND(26) RND(6)
  x0 += ks2; x1 += k0 + 5u;
#undef RND
  o0 = x0; o1 = x1;
}

// bits -> erfinv(u), u ~ U(-1,1), matching jax.random.normal to <=1e-6 (sqrt2 folded into W)
__device__ __forceinline__ float bits_to_erfinv(uint32_t bits) {
  const float lo = __uint_as_float(0xBF7FFFFFu);                 // -(1-2^-24)
  float m = __uint_as_float((bits >> 9) | 0x3F800000u);          // [1,2)
  float u = fmaxf(lo, fmaf(m, 2.0f, -3.0f));                     // (-1,1); clamp REQUIRED (m==1 -> log(0))
  float t = fmaf(-u, u, 1.0f);                                   // 1-u^2, single-rounded
  float L = __log2f(t);                                          // v_log_f32, L <= 0
  float p;
  if (L > -7.2134752f) {                                         // w = -ln2*L < 5
    float w = fmaf(L, -0.69314718056f, -2.5f);
    p = 2.81022636e-08f;
    p = fmaf(p, w, 3.43273939e-07f);
    p = fmaf(p, w, -3.5233877e-06f);
    p = fmaf(p, w, -4.39150654e-06f);
    p = fmaf(p, w, 0.00021858087f);
    p = fmaf(p, w, -0.00125372503f);
    p = fmaf(p, w, -0.00417768164f);
    p = fmaf(p, w, 0.246640727f);
    p = fmaf(p, w, 1.50140941f);
  } else {
    float w = sqrtf(L * -0.69314718056f) - 3.0f;
    p = -0.000200214257f;
    p = fmaf(p, w, 0.000100950558f);
    p = fmaf(p, w, 0.00134934322f);
    p = fmaf(p, w, -0.00367342844f);
    p = fmaf(p, w, 0.00573950773f);
    p = fmaf(p, w, -0.0076224613f);
    p = fmaf(p, w, 0.00943887047f);
    p = fmaf(p, w, 1.00167406f);
    p = fmaf(p, w, 2.83297682f);
  }
  return p * u;
}

// ---------------- Kernel 1: sde accumulate; 2 pair-items per thread for ILP ----------------
__global__ __launch_bounds__(BLK) void sde_kernel(const float* __restrict__ D_long,
                                                  const float* __restrict__ D_trans,
                                                  const int* __restrict__ delta_us,
                                                  const int* __restrict__ Delta_us,
                                                  const int* __restrict__ dt_us,
                                                  const int* __restrict__ seed,
                                                  float* __restrict__ Sbuf) {
  __shared__ float sA[T_PTS], sB[T_PTS];
  __shared__ uint4 kw[STEPS];                 // (k0, k1, sqrt2*W, pad) -> one ds_read_b128/step
  int tid = threadIdx.x;

  // env into sA (2 iters/thread)
  {
    float u  = (float)dt_us[0]    * 1e-6f;    // rise = dt
    float df = (float)delta_us[0] * 1e-6f;
    float Df = (float)Delta_us[0] * 1e-6f;
    for (int t = tid; t < T_PTS; t += BLK) {
      float tm = (float)t * u;
      float c1 = fminf(fmaxf(tm / u, 0.0f), 1.0f);
      float c2 = fminf(fmaxf((tm - df) / u, 0.0f), 1.0f);
      float c3 = fminf(fmaxf((tm - Df) / u, 0.0f), 1.0f);
      float c4 = fminf(fmaxf(((tm - Df) - df) / u, 0.0f), 1.0f);
      sA[t] = (c1 - c2) - (c3 - c4);
    }
  }
  __syncthreads();

  // suffix-inclusive Hillis-Steele scan (9 rounds, ping-pong): src[i] = sum_{t=i..400} env[t]
  {
    float* src = sA; float* dst = sB;
    for (int d = 1; d < T_PTS; d <<= 1) {
      for (int i = tid; i < T_PTS; i += BLK)
        dst[i] = src[i] + ((i + d < T_PTS) ? src[i + d] : 0.0f);
      __syncthreads();
      float* tmp = src; src = dst; dst = tmp;
    }
    uint32_t sd = (uint32_t)seed[0];
    for (int i = tid; i < STEPS; i += BLK) {
      uint32_t o0, o1;                        // fold_in(key(seed), i)
      threefry2x32(0u, sd, 0u, (uint32_t)i, o0, o1);
      kw[i] = make_uint4(o0, o1, __float_as_uint(1.41421356237309515f * src[i + 1]), 0u);
    }
  }
  __syncthreads();

  // hot loop: 2 pair-items (same chunk) per thread -> 6 independent threefry streams/step
  uint32_t t = blockIdx.x * BLK + tid;        // [0, 250112)
  if (t < SDE_ITEMS) {
    uint32_t chunk = t / QUART_N;             // const divide -> magic mul
    uint32_t q = t - chunk * QUART_N;         // [0, 12500)
    const uint32_t pA = q, pB = q + QUART_N;
    const uint32_t cA = 3u * pA, cB = 3u * pB;
    const int i0 = (int)chunk * SPC;

    float aA0x=0.f, aA0y=0.f, aA0z=0.f;       // particle pA
    float aA1x=0.f, aA1y=0.f, aA1z=0.f;       // particle pA + 25000
    float aB0x=0.f, aB0y=0.f, aB0z=0.f;       // particle pB
    float aB1x=0.f, aB1y=0.f, aB1z=0.f;       // particle pB + 25000

    for (int s = 0; s < SPC; ++s) {
      uint4 k = kw[i0 + s];                   // ds_read_b128 broadcast
      float w = __uint_as_float(k.z);         // sqrt(2) * suffix-weight
      uint32_t oA0, oA1, oB0, oB1;
      threefry2x32(k.x, k.y, cA,      cA + BITS_SPLIT,      oA0, oA1);
      threefry2x32(k.x, k.y, cB,      cB + BITS_SPLIT,      oB0, oB1);
      aA0x = fmaf(w, bits_to_erfinv(oA0), aA0x);
      aA1x = fmaf(w, bits_to_erfinv(oA1), aA1x);
      aB0x = fmaf(w, bits_to_erfinv(oB0), aB0x);
      aB1x = fmaf(w, bits_to_erfinv(oB1), aB1x);
      threefry2x32(k.x, k.y, cA + 1u, cA + 1u + BITS_SPLIT, oA0, oA1);
      threefry2x32(k.x, k.y, cB + 1u, cB + 1u + BITS_SPLIT, oB0, oB1);
      aA0y = fmaf(w, bits_to_erfinv(oA0), aA0y);
      aA1y = fmaf(w, bits_to_erfinv(oA1), aA1y);
      aB0y = fmaf(w, bits_to_erfinv(oB0), aB0y);
      aB1y = fmaf(w, bits_to_erfinv(oB1), aB1y);
      threefry2x32(k.x, k.y, cA + 2u, cA + 2u + BITS_SPLIT, oA0, oA1);
      threefry2x32(k.x, k.y, cB + 2u, cB + 2u + BITS_SPLIT, oB0, oB1);
      aA0z = fmaf(w, bits_to_erfinv(oA0), aA0z);
      aA1z = fmaf(w, bits_to_erfinv(oA1), aA1z);
      aB0z = fmaf(w, bits_to_erfinv(oB0), aB0z);
      aB1z = fmaf(w, bits_to_erfinv(oB1), aB1z);
    }

    float twodt = 2.0f * ((float)dt_us[0] * 1e-6f);
    float st = sqrtf(twodt * D_trans[0]);
    float sl = sqrtf(twodt * D_long[0]);

    atomicAdd(&Sbuf[3 * pA + 0], aA0x * st);
    atomicAdd(&Sbuf[3 * pA + 1], aA0y * st);
    atomicAdd(&Sbuf[3 * pA + 2], aA0z * sl);
    atomicAdd(&Sbuf[3 * (pA + HALF_N) + 0], aA1x * st);
    atomicAdd(&Sbuf[3 * (pA + HALF_N) + 1], aA1y * st);
    atomicAdd(&Sbuf[3 * (pA + HALF_N) + 2], aA1z * sl);
    atomicAdd(&Sbuf[3 * pB + 0], aB0x * st);
    atomicAdd(&Sbuf[3 * pB + 1], aB0y * st);
    atomicAdd(&Sbuf[3 * pB + 2], aB0z * sl);
    atomicAdd(&Sbuf[3 * (pB + HALF_N) + 0], aB1x * st);
    atomicAdd(&Sbuf[3 * (pB + HALF_N) + 1], aB1y * st);
    atomicAdd(&Sbuf[3 * (pB + HALF_N) + 2], aB1z * sl);
  }
}

// ---------------- Kernel 2: partial cos/sin sums; last block finalizes (proven) ----------------
__global__ __launch_bounds__(BLK) void signal_partial(const float* __restrict__ Sbuf,
                                                      const float* __restrict__ G_amps,
                                                      const float* __restrict__ grad,
                                                      const int* __restrict__ dt_us,
                                                      float* __restrict__ acc,
                                                      float* __restrict__ out) {
  int m = blockIdx.x;
  int n0 = blockIdx.y * (N_PART / NSPLIT);
  int tid = threadIdx.x;
  float Kf = 267.513e6f * ((float)dt_us[0] * 1e-6f);
  float Km = Kf * G_amps[m];
  float gx = grad[3 * m + 0], gy = grad[3 * m + 1], gz = grad[3 * m + 2];

  float cs = 0.f, ss = 0.f;
  for (int n = n0 + tid; n < n0 + N_PART / NSPLIT; n += BLK) {
    float sx = Sbuf[3 * n + 0], sy = Sbuf[3 * n + 1], sz = Sbuf[3 * n + 2];
    float ph = Km * (gx * sx + gy * sy + gz * sz);
    float s, c;
    __sincosf(ph, &s, &c);                 // v_sin_f32 / v_cos_f32
    cs += c; ss += s;
  }
  for (int off = 32; off > 0; off >>= 1) {
    cs += __shfl_down(cs, off);
    ss += __shfl_down(ss, off);
  }
  __shared__ float redc[4], reds[4];
  __shared__ int slast;
  int lane = tid & 63, wv = tid >> 6;
  if (lane == 0) { redc[wv] = cs; reds[wv] = ss; }
  __syncthreads();
  if (tid == 0) {
    atomicAdd(&acc[m],      redc[0] + redc[1] + redc[2] + redc[3]);
    atomicAdd(&acc[64 + m], reds[0] + reds[1] + reds[2] + reds[3]);
    __threadfence();
    unsigned* ctr = (unsigned*)&acc[128];
    unsigned done = __hip_atomic_fetch_add(ctr, 1u, __ATOMIC_ACQ_REL, __HIP_MEMORY_SCOPE_AGENT);
    slast = (done == (unsigned)(gridDim.x * gridDim.y) - 1u) ? 1 : 0;
  }
  __syncthreads();
  if (slast && tid < (int)gridDim.x) {
    float c = __hip_atomic_load(&acc[tid],      __ATOMIC_RELAXED, __HIP_MEMORY_SCOPE_AGENT) / (float)N_PART;
    float s = __hip_atomic_load(&acc[64 + tid], __ATOMIC_RELAXED, __HIP_MEMORY_SCOPE_AGENT) / (float)N_PART;
    out[tid] = sqrtf(c * c + s * s);
  }
}

extern "C" void kernel_launch(void* const* d_in, const int* in_sizes, int n_in,
                              void* d_out, int out_size, void* d_ws, size_t ws_size,
                              hipStream_t stream) {
  const float* G_amps   = (const float*)d_in[0];
  const float* grad     = (const float*)d_in[1];
  const float* D_long   = (const float*)d_in[2];
  const float* D_trans  = (const float*)d_in[3];
  const int*   delta_us = (const int*)d_in[4];
  const int*   Delta_us = (const int*)d_in[5];
  const int*   dt_us    = (const int*)d_in[6];
  const int*   seed     = (const int*)d_in[8];

  // ws layout: Sbuf[150000] f32 (600000B) | acc[128] f32 + ctr u32 (516B)
  float* Sbuf = (float*)d_ws;
  float* acc  = (float*)((char*)d_ws + 600000);

  hipMemsetAsync(d_ws, 0, 600520, stream);
  int sde_blocks = (SDE_ITEMS + BLK - 1) / BLK;   // 977
  sde_kernel<<<sde_blocks, BLK, 0, stream>>>(D_long, D_trans, delta_us, Delta_us,
                                             dt_us, seed, Sbuf);
  int M = in_sizes[0];
  signal_partial<<<dim3(M, NSPLIT), BLK, 0, stream>>>(Sbuf, G_amps, grad, dt_us,
                                                      acc, (float*)d_out);
}